// Round 4
// baseline (191.374 us; speedup 1.0000x reference)
//
#include <hip/hip_runtime.h>
#include <hip/hip_bf16.h>
#include <stdint.h>

#define B_SZ 1024
#define M_SZ 209
#define MPAD 224            // padded M rows (14 * 16)
#define D_SZ 12288
#define KC   16             // split-K chunks
#define KCH  768            // K elems per chunk (D/KC)
#define BK   128            // K per staging iteration (fp8 bytes == elems)
#define NIT  (KCH / BK)     // 6
#define NB   32             // B splits -> grid (16,32) = 512 blocks = 2/CU
#define BT   32             // B rows per block
#define NCT  7              // 16-wide col tiles per wave (ct-half)
#define SROW 224            // slab k-stride (fp8 BYTES)
#define SLROW (KC * SROW)   // 3584

// ws byte offsets
#define CBF_OFF  0u                                   // c fp8 [224][12288] (2.75 MB)
#define XXP_OFF  (MPAD * D_SZ)                        // xx partials [B][KC] f32 (64 KB)
#define CCP_OFF  (XXP_OFF + B_SZ * KC * 4)            // cc halves [224][2] f32
#define SLAB_OFF (CCP_OFF + MPAD * 2 * 4)             // slab [B][KC][224] fp8 (3.67 MB)
#define CNT_OFF  (SLAB_OFF + B_SZ * SLROW)            // per-b done counters [32] u32

typedef __attribute__((ext_vector_type(4))) float floatx4;

__device__ __forceinline__ uint32_t pk8x4(const float4& v) {
    int d = __builtin_amdgcn_cvt_pk_fp8_f32(v.x, v.y, 0, false);
    d     = __builtin_amdgcn_cvt_pk_fp8_f32(v.z, v.w, d, true);
    return (uint32_t)d;
}

__device__ __forceinline__ void gload_lds16(const void* g, void* l) {
    __builtin_amdgcn_global_load_lds(
        (const __attribute__((address_space(1))) void*)g,
        (__attribute__((address_space(3))) void*)l, 16, 0, 0);
}

// ---------------------------------------------------------------------------
// prepass: c fp32 -> fp8 e4m3 (padded to 224 rows, zeros) + ||c||^2 halves.
// Also zeroes the per-b done counters (ws is harness-poisoned).
__global__ __launch_bounds__(256) void rbf_prep(
    const float* __restrict__ c, uint8_t* __restrict__ cf8,
    float* __restrict__ ccp, uint32_t* __restrict__ cnt)
{
    __shared__ float red[4];
    const int j = blockIdx.x >> 1, h = blockIdx.x & 1;
    const int t = threadIdx.x;
    if (blockIdx.x == 0 && t < NB) cnt[t] = 0u;
    const int base = h * (D_SZ / 2);
    uint8_t* dst = cf8 + (size_t)j * D_SZ + base;
    float s = 0.f;
    if (j < M_SZ) {
        const float* src = c + (size_t)j * D_SZ + base;
        for (int i = t * 8; i < D_SZ / 2; i += 2048) {
            float4 v0 = *(const float4*)(src + i);
            float4 v1 = *(const float4*)(src + i + 4);
            s += v0.x*v0.x + v0.y*v0.y + v0.z*v0.z + v0.w*v0.w
               + v1.x*v1.x + v1.y*v1.y + v1.z*v1.z + v1.w*v1.w;
            uint2 w = { pk8x4(v0), pk8x4(v1) };
            *(uint2*)(dst + i) = w;
        }
    } else {
        uint2 zz = {0u, 0u};
        for (int i = t * 8; i < D_SZ / 2; i += 2048) *(uint2*)(dst + i) = zz;
    }
#pragma unroll
    for (int off = 32; off > 0; off >>= 1) s += __shfl_down(s, off);
    if ((t & 63) == 0) red[t >> 6] = s;
    __syncthreads();
    if (t == 0) ccp[j * 2 + h] = red[0] + red[1] + red[2] + red[3];
}

// ---------------------------------------------------------------------------
// main: split-K distance GEMM (dbuf staging, 16x16x32 fp8 MFMA), slab/xxp
// stores, then a deadlock-free last-block-per-b fin tail: the 16th arriver
// of each b-group computes the radial+W epilogue for rows b*32..b*32+31
// (one wave per 8 rows, in-register, no LDS).
__global__ __launch_bounds__(256, 2) void rbf_main(
    const float* __restrict__ x, const uint8_t* __restrict__ cf8,
    uint8_t* __restrict__ slab, float* __restrict__ xxp,
    uint32_t* __restrict__ cnt, const float* __restrict__ ccp,
    const float* __restrict__ sigma, const float* __restrict__ W,
    const float* __restrict__ bias, float* __restrict__ out)
{
    __shared__ uint8_t sx[2][BT * BK];     //  8 KB
    __shared__ uint8_t sc[2][MPAD * BK];   // 56 KB  (64 KB total -> 2 blocks/CU)

    const int t    = threadIdx.x;
    const int k    = blockIdx.x;
    const int b    = blockIdx.y;
    const int wave = t >> 6, lane = t & 63;
    const int quad = lane >> 4, mrow = lane & 15;
    const int qh = quad >> 1, ql = quad & 1;
    const int s2 = (mrow >> 1) & 7;
    const int rt  = wave & 1;           // row-tile (16 rows)
    const int cth = wave >> 1;          // ct-half (7 tiles)

    floatx4 acc[NCT];
    const floatx4 z4 = {0.f, 0.f, 0.f, 0.f};
#pragma unroll
    for (int i = 0; i < NCT; ++i) acc[i] = z4;

    // ---- c-DMA lane source pointers (R8-verified mapping).
    const int oE = (((lane & 7) ^ (lane >> 4)) & 7) * 16;
    const int oO = ((((lane & 7) ^ (lane >> 4)) ^ 4) & 7) * 16;
    const uint8_t* cpbE = cf8 + (size_t)(lane >> 3) * D_SZ + (size_t)k * KCH + oE;
    const uint8_t* cpbO = cf8 + (size_t)(lane >> 3) * D_SZ + (size_t)k * KCH + oO;

    // ---- issue iter-0 c-DMA into sc[0] (in flight across whole x prologue)
#pragma unroll
    for (int jj = 0; jj < 7; ++jj) {
        const int cr = wave * 7 + jj;
        const uint8_t* p = ((cr & 1) ? cpbO : cpbE) + (size_t)cr * 8 * D_SZ;
        gload_lds16(p, &sc[0][cr * 1024]);
    }

    // ---- x prologue: 8 threads/row, 16 floats each per iter -> fp8 uint4
    const int xr = t >> 3;              // staging row 0..31
    const int xc = t & 7;               // 16-float column group
    const float* xp = x + (size_t)(b * BT + xr) * D_SZ + (size_t)k * KCH + xc * 16;

    uint4 xw[NIT];
    float sxx = 0.f;
#pragma unroll
    for (int it = 0; it < NIT; ++it) {
        float4 v0 = *(const float4*)(xp + it * BK + 0);
        float4 v1 = *(const float4*)(xp + it * BK + 4);
        float4 v2 = *(const float4*)(xp + it * BK + 8);
        float4 v3 = *(const float4*)(xp + it * BK + 12);
        sxx += v0.x*v0.x + v0.y*v0.y + v0.z*v0.z + v0.w*v0.w
             + v1.x*v1.x + v1.y*v1.y + v1.z*v1.z + v1.w*v1.w
             + v2.x*v2.x + v2.y*v2.y + v2.z*v2.z + v2.w*v2.w
             + v3.x*v3.x + v3.y*v3.y + v3.z*v3.z + v3.w*v3.w;
        xw[it] = make_uint4(pk8x4(v0), pk8x4(v1), pk8x4(v2), pk8x4(v3));
    }
    // sx dest: row xr, chunk16 = xc ^ ((xr>>1)&7)
    const int sxoff = xr * BK + ((xc ^ ((xr >> 1) & 7)) & 7) * 16;

    // ---- fragment offsets (shared by A and B; rows have same s2 law)
    int boff[4];
#pragma unroll
    for (int ks = 0; ks < 4; ++ks)
        boff[ks] = (((ks * 2 + qh) ^ s2) & 7) * 16 + ql * 8;
    const int aoff  = (rt * 16 + mrow) * BK;
    const int boff0 = (cth * 7 * 16 + mrow) * BK;

    *(uint4*)&sx[0][sxoff] = xw[0];
    __syncthreads();   // drains DMA(0) + sx writes

#pragma unroll
    for (int it = 0; it < NIT; ++it) {
        const int cur = it & 1;
        // issue next-iter staging first (flies during MFMA phase)
        if (it + 1 < NIT) {
#pragma unroll
            for (int jj = 0; jj < 7; ++jj) {
                const int cr = wave * 7 + jj;
                const uint8_t* p = ((cr & 1) ? cpbO : cpbE)
                                 + (size_t)cr * 8 * D_SZ + (it + 1) * BK;
                gload_lds16(p, &sc[cur ^ 1][cr * 1024]);
            }
            *(uint4*)&sx[cur ^ 1][sxoff] = xw[it + 1];
        }
        // MFMA phase on current buffers
#pragma unroll
        for (int ks = 0; ks < 4; ++ks) {
            const long a = *(const long*)(&sx[cur][aoff] + boff[ks]);
#pragma unroll
            for (int ct = 0; ct < NCT; ++ct) {
                const long bv = *(const long*)(&sc[cur][boff0] + ct * 16 * BK + boff[ks]);
                acc[ct] = __builtin_amdgcn_mfma_f32_16x16x32_fp8_fp8(a, bv, acc[ct], 0, 0, 0);
            }
        }
        __syncthreads();
    }

    // ---- slab write: [i][k][224] fp8 e4m3. C/D: col=lane&15, row=quad*4+reg
    {
        uint8_t* sd = slab + (size_t)k * SROW;
        const int gi0 = b * BT + rt * 16 + quad * 4;
#pragma unroll
        for (int ct = 0; ct < NCT; ++ct) {
            const int gj = (cth * 7 + ct) * 16 + mrow;
            const int p01 = __builtin_amdgcn_cvt_pk_fp8_f32(acc[ct][0], acc[ct][1], 0, false);
            const int p23 = __builtin_amdgcn_cvt_pk_fp8_f32(acc[ct][2], acc[ct][3], 0, false);
            uint8_t* wb = sd + (size_t)gi0 * SLROW + gj;
            wb[0]                 = (uint8_t)(p01 & 0xff);
            wb[SLROW]             = (uint8_t)((p01 >> 8) & 0xff);
            wb[2 * (size_t)SLROW] = (uint8_t)(p23 & 0xff);
            wb[3 * (size_t)SLROW] = (uint8_t)((p23 >> 8) & 0xff);
        }
        sxx += __shfl_down(sxx, 4);
        sxx += __shfl_down(sxx, 2);
        sxx += __shfl_down(sxx, 1);
        if ((t & 7) == 0) xxp[(size_t)(b * BT + xr) * KC + k] = sxx;
    }

    // ---- last-block-per-b fin tail (deadlock-free, no grid sync) ----------
    __threadfence();                    // release: slab/xxp globally visible
    __syncthreads();                    // all waves' stores fenced
    int* flag = (int*)&sx[0][0];        // sx dead now; reuse as LDS flag
    if (t == 0) {
        const uint32_t old = atomicAdd(&cnt[b], 1u);
        *flag = (old == (uint32_t)(KC - 1)) ? 1 : 0;
    }
    __syncthreads();
    if (*flag == 0) return;             // not last -> done
    __threadfence();                    // acquire: peers' slab/xxp visible

    const float b0 = bias[0], b1 = bias[1];
    // wave handles rows b*32 + wave*8 .. +7; lane owns columns 4*lane..4*lane+3
#pragma unroll
    for (int r = 0; r < 8; ++r) {
        const int i = b * BT + wave * 8 + r;

        // xx_i = sum over KC chunks
        float xv = (lane < KC) ? xxp[(size_t)i * KC + lane] : 0.f;
#pragma unroll
        for (int off = 32; off > 0; off >>= 1) xv += __shfl_down(xv, off);
        const float xxi = __shfl(xv, 0);

        // jtot for 4 columns: sum over KC of fp8 slab
        float jt0 = 0.f, jt1 = 0.f, jt2 = 0.f, jt3 = 0.f;
        if (lane < 56) {
            const uint8_t* sp = slab + (size_t)i * SLROW + lane * 4;
#pragma unroll
            for (int kk = 0; kk < KC; ++kk) {
                const int v = *(const int*)(sp + kk * SROW);
                jt0 += __builtin_amdgcn_cvt_f32_fp8(v, 0);
                jt1 += __builtin_amdgcn_cvt_f32_fp8(v, 1);
                jt2 += __builtin_amdgcn_cvt_f32_fp8(v, 2);
                jt3 += __builtin_amdgcn_cvt_f32_fp8(v, 3);
            }
        }

        // epilogue for the 4 owned columns
        float a0 = 0.f, a1 = 0.f;
        const float jt[4] = { jt0, jt1, jt2, jt3 };
#pragma unroll
        for (int e = 0; e < 4; ++e) {
            const int j = lane * 4 + e;
            if (j < M_SZ) {
                const float ccj = ccp[j * 2] + ccp[j * 2 + 1];
                const float d2 = fmaxf(xxi + ccj - 2.f * jt[e], 0.f);
                const float sg = sigma[j];
                const float rad = __expf(-sqrtf(d2) / (sg * sg));
                a0 += rad * W[j];
                a1 += rad * W[M_SZ + j];
            }
        }
#pragma unroll
        for (int off = 32; off > 0; off >>= 1) {
            a0 += __shfl_down(a0, off);
            a1 += __shfl_down(a1, off);
        }
        if (lane == 0) {
            out[i * 2 + 0] = a0 + b0;
            out[i * 2 + 1] = a1 + b1;
        }
    }
}

// ---------------------------------------------------------------------------
extern "C" void kernel_launch(void* const* d_in, const int* in_sizes, int n_in,
                              void* d_out, int out_size, void* d_ws, size_t ws_size,
                              hipStream_t stream)
{
    const float* x     = (const float*)d_in[0];
    const float* c     = (const float*)d_in[1];
    const float* sigma = (const float*)d_in[2];
    const float* W     = (const float*)d_in[3];
    const float* bias  = (const float*)d_in[4];
    float* out = (float*)d_out;

    char* ws = (char*)d_ws;
    uint8_t*  cf8  = (uint8_t*)(ws + CBF_OFF);
    float*    xxp  = (float*)(ws + XXP_OFF);
    float*    ccp  = (float*)(ws + CCP_OFF);
    uint8_t*  slab = (uint8_t*)(ws + SLAB_OFF);
    uint32_t* cnt  = (uint32_t*)(ws + CNT_OFF);

    rbf_prep<<<MPAD * 2, 256, 0, stream>>>(c, cf8, ccp, cnt);
    rbf_main<<<dim3(KC, NB), 256, 0, stream>>>(x, cf8, slab, xxp, cnt,
                                               ccp, sigma, W, bias, out);
}

// Round 5
// 124.699 us; speedup vs baseline: 1.5347x; 1.5347x over previous
//
#include <hip/hip_runtime.h>
#include <hip/hip_bf16.h>
#include <stdint.h>

#define B_SZ 1024
#define M_SZ 209
#define MPAD 224            // padded M rows (14 * 16)
#define D_SZ 12288
#define KC   16             // split-K chunks
#define KCH  768            // K elems per chunk (D/KC)
#define BK   128            // K per staging iteration (fp8 bytes == elems)
#define NIT  (KCH / BK)     // 6
#define NB   32             // B splits -> grid (16,32) = 512 blocks = 2/CU
#define BT   32             // B rows per block
#define NCT  7              // 16-wide col tiles per wave (ct-half)
#define SROW 224            // slab k-stride (fp8 BYTES)
#define SLROW (KC * SROW)   // 3584

// ws byte offsets
#define CBF_OFF  0u                                   // c fp8 [224][12288] (2.75 MB)
#define XXP_OFF  (MPAD * D_SZ)                        // xx partials [B][KC] f32 (64 KB)
#define CCP_OFF  (XXP_OFF + B_SZ * KC * 4)            // cc halves [224][2] f32
#define SLAB_OFF (CCP_OFF + MPAD * 2 * 4)             // slab [B][KC][224] fp8 (3.67 MB)
#define CNT_OFF  (SLAB_OFF + B_SZ * SLROW)            // per-b done counters [32] u32

typedef __attribute__((ext_vector_type(4))) float floatx4;

// Agent-scope coherent (sc0|sc1) relaxed ops: write-through to / read from
// the chip-coherent point (L3), no wbl2/inv fences. This is the mechanism
// that replaces R4's catastrophic __threadfence (512 serialized L2 flushes).
#define ST_AGENT(p, v) __hip_atomic_store((p), (v), __ATOMIC_RELAXED, __HIP_MEMORY_SCOPE_AGENT)
#define LD_AGENT(p)    __hip_atomic_load((p), __ATOMIC_RELAXED, __HIP_MEMORY_SCOPE_AGENT)

__device__ __forceinline__ uint32_t pk8x4(const float4& v) {
    int d = __builtin_amdgcn_cvt_pk_fp8_f32(v.x, v.y, 0, false);
    d     = __builtin_amdgcn_cvt_pk_fp8_f32(v.z, v.w, d, true);
    return (uint32_t)d;
}

__device__ __forceinline__ void gload_lds16(const void* g, void* l) {
    __builtin_amdgcn_global_load_lds(
        (const __attribute__((address_space(1))) void*)g,
        (__attribute__((address_space(3))) void*)l, 16, 0, 0);
}

// ---------------------------------------------------------------------------
// prepass: c fp32 -> fp8 e4m3 (padded to 224 rows, zeros) + ||c||^2 halves.
// Also zeroes the per-b done counters (ws is harness-poisoned).
__global__ __launch_bounds__(256) void rbf_prep(
    const float* __restrict__ c, uint8_t* __restrict__ cf8,
    float* __restrict__ ccp, uint32_t* __restrict__ cnt)
{
    __shared__ float red[4];
    const int j = blockIdx.x >> 1, h = blockIdx.x & 1;
    const int t = threadIdx.x;
    if (blockIdx.x == 0 && t < NB) cnt[t] = 0u;
    const int base = h * (D_SZ / 2);
    uint8_t* dst = cf8 + (size_t)j * D_SZ + base;
    float s = 0.f;
    if (j < M_SZ) {
        const float* src = c + (size_t)j * D_SZ + base;
        for (int i = t * 8; i < D_SZ / 2; i += 2048) {
            float4 v0 = *(const float4*)(src + i);
            float4 v1 = *(const float4*)(src + i + 4);
            s += v0.x*v0.x + v0.y*v0.y + v0.z*v0.z + v0.w*v0.w
               + v1.x*v1.x + v1.y*v1.y + v1.z*v1.z + v1.w*v1.w;
            uint2 w = { pk8x4(v0), pk8x4(v1) };
            *(uint2*)(dst + i) = w;
        }
    } else {
        uint2 zz = {0u, 0u};
        for (int i = t * 8; i < D_SZ / 2; i += 2048) *(uint2*)(dst + i) = zz;
    }
#pragma unroll
    for (int off = 32; off > 0; off >>= 1) s += __shfl_down(s, off);
    if ((t & 63) == 0) red[t >> 6] = s;
    __syncthreads();
    if (t == 0) ccp[j * 2 + h] = red[0] + red[1] + red[2] + red[3];
}

// ---------------------------------------------------------------------------
// main: split-K distance GEMM (dbuf staging, 16x16x32 fp8 MFMA). slab/xxp
// stored with agent-coherent (sc0|sc1) relaxed stores -> land at L3 without
// any cache-flush fence. Last-block-per-b tail (16th arriver via atomicAdd)
// reads them back with agent-coherent loads and runs the radial+W epilogue
// for rows b*32..b*32+31 in-register.
__global__ __launch_bounds__(256, 2) void rbf_main(
    const float* __restrict__ x, const uint8_t* __restrict__ cf8,
    uint8_t* __restrict__ slab, float* __restrict__ xxp,
    uint32_t* __restrict__ cnt, const float* __restrict__ ccp,
    const float* __restrict__ sigma, const float* __restrict__ W,
    const float* __restrict__ bias, float* __restrict__ out)
{
    __shared__ uint8_t sx[2][BT * BK];     //  8 KB
    __shared__ uint8_t sc[2][MPAD * BK];   // 56 KB  (64 KB total -> 2 blocks/CU)

    const int t    = threadIdx.x;
    const int k    = blockIdx.x;
    const int b    = blockIdx.y;
    const int wave = t >> 6, lane = t & 63;
    const int quad = lane >> 4, mrow = lane & 15;
    const int qh = quad >> 1, ql = quad & 1;
    const int s2 = (mrow >> 1) & 7;
    const int rt  = wave & 1;           // row-tile (16 rows)
    const int cth = wave >> 1;          // ct-half (7 tiles)

    floatx4 acc[NCT];
    const floatx4 z4 = {0.f, 0.f, 0.f, 0.f};
#pragma unroll
    for (int i = 0; i < NCT; ++i) acc[i] = z4;

    // ---- c-DMA lane source pointers (R8-verified mapping).
    const int oE = (((lane & 7) ^ (lane >> 4)) & 7) * 16;
    const int oO = ((((lane & 7) ^ (lane >> 4)) ^ 4) & 7) * 16;
    const uint8_t* cpbE = cf8 + (size_t)(lane >> 3) * D_SZ + (size_t)k * KCH + oE;
    const uint8_t* cpbO = cf8 + (size_t)(lane >> 3) * D_SZ + (size_t)k * KCH + oO;

    // ---- issue iter-0 c-DMA into sc[0] (in flight across whole x prologue)
#pragma unroll
    for (int jj = 0; jj < 7; ++jj) {
        const int cr = wave * 7 + jj;
        const uint8_t* p = ((cr & 1) ? cpbO : cpbE) + (size_t)cr * 8 * D_SZ;
        gload_lds16(p, &sc[0][cr * 1024]);
    }

    // ---- x prologue: 8 threads/row, 16 floats each per iter -> fp8 uint4
    const int xr = t >> 3;              // staging row 0..31
    const int xc = t & 7;               // 16-float column group
    const float* xp = x + (size_t)(b * BT + xr) * D_SZ + (size_t)k * KCH + xc * 16;

    uint4 xw[NIT];
    float sxx = 0.f;
#pragma unroll
    for (int it = 0; it < NIT; ++it) {
        float4 v0 = *(const float4*)(xp + it * BK + 0);
        float4 v1 = *(const float4*)(xp + it * BK + 4);
        float4 v2 = *(const float4*)(xp + it * BK + 8);
        float4 v3 = *(const float4*)(xp + it * BK + 12);
        sxx += v0.x*v0.x + v0.y*v0.y + v0.z*v0.z + v0.w*v0.w
             + v1.x*v1.x + v1.y*v1.y + v1.z*v1.z + v1.w*v1.w
             + v2.x*v2.x + v2.y*v2.y + v2.z*v2.z + v2.w*v2.w
             + v3.x*v3.x + v3.y*v3.y + v3.z*v3.z + v3.w*v3.w;
        xw[it] = make_uint4(pk8x4(v0), pk8x4(v1), pk8x4(v2), pk8x4(v3));
    }
    // sx dest: row xr, chunk16 = xc ^ ((xr>>1)&7)
    const int sxoff = xr * BK + ((xc ^ ((xr >> 1) & 7)) & 7) * 16;

    // ---- fragment offsets (shared by A and B; rows have same s2 law)
    int boff[4];
#pragma unroll
    for (int ks = 0; ks < 4; ++ks)
        boff[ks] = (((ks * 2 + qh) ^ s2) & 7) * 16 + ql * 8;
    const int aoff  = (rt * 16 + mrow) * BK;
    const int boff0 = (cth * 7 * 16 + mrow) * BK;

    *(uint4*)&sx[0][sxoff] = xw[0];
    __syncthreads();   // drains DMA(0) + sx writes

#pragma unroll
    for (int it = 0; it < NIT; ++it) {
        const int cur = it & 1;
        // issue next-iter staging first (flies during MFMA phase)
        if (it + 1 < NIT) {
#pragma unroll
            for (int jj = 0; jj < 7; ++jj) {
                const int cr = wave * 7 + jj;
                const uint8_t* p = ((cr & 1) ? cpbO : cpbE)
                                 + (size_t)cr * 8 * D_SZ + (it + 1) * BK;
                gload_lds16(p, &sc[cur ^ 1][cr * 1024]);
            }
            *(uint4*)&sx[cur ^ 1][sxoff] = xw[it + 1];
        }
        // MFMA phase on current buffers
#pragma unroll
        for (int ks = 0; ks < 4; ++ks) {
            const long a = *(const long*)(&sx[cur][aoff] + boff[ks]);
#pragma unroll
            for (int ct = 0; ct < NCT; ++ct) {
                const long bv = *(const long*)(&sc[cur][boff0] + ct * 16 * BK + boff[ks]);
                acc[ct] = __builtin_amdgcn_mfma_f32_16x16x32_fp8_fp8(a, bv, acc[ct], 0, 0, 0);
            }
        }
        __syncthreads();
    }

    // ---- slab write: [i][k][224] fp8 e4m3, agent-coherent stores (-> L3)
    {
        uint8_t* sd = slab + (size_t)k * SROW;
        const int gi0 = b * BT + rt * 16 + quad * 4;
#pragma unroll
        for (int ct = 0; ct < NCT; ++ct) {
            const int gj = (cth * 7 + ct) * 16 + mrow;
            const int p01 = __builtin_amdgcn_cvt_pk_fp8_f32(acc[ct][0], acc[ct][1], 0, false);
            const int p23 = __builtin_amdgcn_cvt_pk_fp8_f32(acc[ct][2], acc[ct][3], 0, false);
            uint8_t* wb = sd + (size_t)gi0 * SLROW + gj;
            ST_AGENT(wb,                     (uint8_t)(p01 & 0xff));
            ST_AGENT(wb + SLROW,             (uint8_t)((p01 >> 8) & 0xff));
            ST_AGENT(wb + 2 * (size_t)SLROW, (uint8_t)(p23 & 0xff));
            ST_AGENT(wb + 3 * (size_t)SLROW, (uint8_t)((p23 >> 8) & 0xff));
        }
        sxx += __shfl_down(sxx, 4);
        sxx += __shfl_down(sxx, 2);
        sxx += __shfl_down(sxx, 1);
        if ((t & 7) == 0) ST_AGENT(&xxp[(size_t)(b * BT + xr) * KC + k], sxx);
    }

    // ---- last-block-per-b fin tail (no cache-flush fences) ----------------
    // Each thread waits for its own sc1 stores to reach the coherence point,
    // then the block-wide barrier makes t0's atomicAdd a release for all.
    asm volatile("s_waitcnt vmcnt(0)" ::: "memory");
    __syncthreads();
    int* flag = (int*)&sx[0][0];        // sx dead now; reuse as LDS flag
    if (t == 0) {
        const uint32_t old = atomicAdd(&cnt[b], 1u);
        *flag = (old == (uint32_t)(KC - 1)) ? 1 : 0;
    }
    __syncthreads();
    if (*flag == 0) return;             // not last -> done

    const float b0 = bias[0], b1 = bias[1];
    // wave handles rows b*32 + wave*8 .. +7; lane owns columns 4*lane..4*lane+3
#pragma unroll
    for (int r = 0; r < 8; ++r) {
        const int i = b * BT + wave * 8 + r;

        // xx_i = sum over KC chunks (agent-coherent reads)
        float xv = (lane < KC) ? LD_AGENT(&xxp[(size_t)i * KC + lane]) : 0.f;
#pragma unroll
        for (int off = 32; off > 0; off >>= 1) xv += __shfl_down(xv, off);
        const float xxi = __shfl(xv, 0);

        // jtot for 4 columns: sum over KC of fp8 slab (agent-coherent reads)
        float jt0 = 0.f, jt1 = 0.f, jt2 = 0.f, jt3 = 0.f;
        if (lane < 56) {
            const uint8_t* sp = slab + (size_t)i * SLROW + lane * 4;
#pragma unroll
            for (int kk = 0; kk < KC; ++kk) {
                const int v = LD_AGENT((const int*)(sp + kk * SROW));
                jt0 += __builtin_amdgcn_cvt_f32_fp8(v, 0);
                jt1 += __builtin_amdgcn_cvt_f32_fp8(v, 1);
                jt2 += __builtin_amdgcn_cvt_f32_fp8(v, 2);
                jt3 += __builtin_amdgcn_cvt_f32_fp8(v, 3);
            }
        }

        // epilogue for the 4 owned columns
        float a0 = 0.f, a1 = 0.f;
        const float jt[4] = { jt0, jt1, jt2, jt3 };
#pragma unroll
        for (int e = 0; e < 4; ++e) {
            const int j = lane * 4 + e;
            if (j < M_SZ) {
                const float ccj = ccp[j * 2] + ccp[j * 2 + 1];
                const float d2 = fmaxf(xxi + ccj - 2.f * jt[e], 0.f);
                const float sg = sigma[j];
                const float rad = __expf(-sqrtf(d2) / (sg * sg));
                a0 += rad * W[j];
                a1 += rad * W[M_SZ + j];
            }
        }
#pragma unroll
        for (int off = 32; off > 0; off >>= 1) {
            a0 += __shfl_down(a0, off);
            a1 += __shfl_down(a1, off);
        }
        if (lane == 0) {
            out[i * 2 + 0] = a0 + b0;
            out[i * 2 + 1] = a1 + b1;
        }
    }
}

// ---------------------------------------------------------------------------
extern "C" void kernel_launch(void* const* d_in, const int* in_sizes, int n_in,
                              void* d_out, int out_size, void* d_ws, size_t ws_size,
                              hipStream_t stream)
{
    const float* x     = (const float*)d_in[0];
    const float* c     = (const float*)d_in[1];
    const float* sigma = (const float*)d_in[2];
    const float* W     = (const float*)d_in[3];
    const float* bias  = (const float*)d_in[4];
    float* out = (float*)d_out;

    char* ws = (char*)d_ws;
    uint8_t*  cf8  = (uint8_t*)(ws + CBF_OFF);
    float*    xxp  = (float*)(ws + XXP_OFF);
    float*    ccp  = (float*)(ws + CCP_OFF);
    uint8_t*  slab = (uint8_t*)(ws + SLAB_OFF);
    uint32_t* cnt  = (uint32_t*)(ws + CNT_OFF);

    rbf_prep<<<MPAD * 2, 256, 0, stream>>>(c, cf8, ccp, cnt);
    rbf_main<<<dim3(KC, NB), 256, 0, stream>>>(x, cf8, slab, xxp, cnt,
                                               ccp, sigma, W, bias, out);
}

// Round 6
// 124.248 us; speedup vs baseline: 1.5403x; 1.0036x over previous
//
#include <hip/hip_runtime.h>
#include <hip/hip_bf16.h>
#include <stdint.h>

#define B_SZ 1024
#define M_SZ 209
#define MPAD 224            // padded M rows (14 * 16)
#define D_SZ 12288
#define KC   16             // split-K chunks
#define KCH  768            // K elems per chunk (D/KC)
#define BK   128            // K per staging iteration (fp8 bytes == elems)
#define NIT  (KCH / BK)     // 6
#define NB   32             // B splits -> grid (16,32) = 512 blocks = 2/CU
#define BT   32             // B rows per block
#define NCT  7              // 16-wide col tiles per wave (ct-half)
#define SROW 224            // slab k-stride (fp8 BYTES)
#define SLROW (KC * SROW)   // 3584

// ws byte offsets
#define CBF_OFF  0u                                   // c fp8 [224][12288] (2.75 MB)
#define XXP_OFF  (MPAD * D_SZ)                        // xx partials [B][KC] f32 (64 KB)
#define CCP_OFF  (XXP_OFF + B_SZ * KC * 4)            // cc halves [224][2] f32
#define SLAB_OFF (CCP_OFF + MPAD * 2 * 4)             // slab [B][KC][224] fp8 (3.67 MB)
#define CNT_OFF  (SLAB_OFF + B_SZ * SLROW)            // per-b done counters [32] u32

typedef __attribute__((ext_vector_type(4))) float floatx4;
typedef __attribute__((ext_vector_type(4))) unsigned int uint32x4;

// Agent-scope coherent relaxed ops (sc0|sc1): write-through to / read from
// the chip-coherent point (L3). No wbl2/inv fences (R4's disaster).
#define ST_AGENT(p, v) __hip_atomic_store((p), (v), __ATOMIC_RELAXED, __HIP_MEMORY_SCOPE_AGENT)
#define LD_AGENT(p)    __hip_atomic_load((p), __ATOMIC_RELAXED, __HIP_MEMORY_SCOPE_AGENT)

__device__ __forceinline__ uint32_t pk8x4(const float4& v) {
    int d = __builtin_amdgcn_cvt_pk_fp8_f32(v.x, v.y, 0, false);
    d     = __builtin_amdgcn_cvt_pk_fp8_f32(v.z, v.w, d, true);
    return (uint32_t)d;
}

__device__ __forceinline__ void gload_lds16(const void* g, void* l) {
    __builtin_amdgcn_global_load_lds(
        (const __attribute__((address_space(1))) void*)g,
        (__attribute__((address_space(3))) void*)l, 16, 0, 0);
}

// ---------------------------------------------------------------------------
// prepass: c fp32 -> fp8 e4m3 (padded to 224 rows, zeros) + ||c||^2 halves.
// Also zeroes the per-b done counters (ws is harness-poisoned).
__global__ __launch_bounds__(256) void rbf_prep(
    const float* __restrict__ c, uint8_t* __restrict__ cf8,
    float* __restrict__ ccp, uint32_t* __restrict__ cnt)
{
    __shared__ float red[4];
    const int j = blockIdx.x >> 1, h = blockIdx.x & 1;
    const int t = threadIdx.x;
    if (blockIdx.x == 0 && t < NB) cnt[t] = 0u;
    const int base = h * (D_SZ / 2);
    uint8_t* dst = cf8 + (size_t)j * D_SZ + base;
    float s = 0.f;
    if (j < M_SZ) {
        const float* src = c + (size_t)j * D_SZ + base;
        for (int i = t * 8; i < D_SZ / 2; i += 2048) {
            float4 v0 = *(const float4*)(src + i);
            float4 v1 = *(const float4*)(src + i + 4);
            s += v0.x*v0.x + v0.y*v0.y + v0.z*v0.z + v0.w*v0.w
               + v1.x*v1.x + v1.y*v1.y + v1.z*v1.z + v1.w*v1.w;
            uint2 w = { pk8x4(v0), pk8x4(v1) };
            *(uint2*)(dst + i) = w;
        }
    } else {
        uint2 zz = {0u, 0u};
        for (int i = t * 8; i < D_SZ / 2; i += 2048) *(uint2*)(dst + i) = zz;
    }
#pragma unroll
    for (int off = 32; off > 0; off >>= 1) s += __shfl_down(s, off);
    if ((t & 63) == 0) red[t >> 6] = s;
    __syncthreads();
    if (t == 0) ccp[j * 2 + h] = red[0] + red[1] + red[2] + red[3];
}

// ---------------------------------------------------------------------------
// main: split-K distance GEMM (dbuf staging, 16x16x32 fp8 MFMA). Slab results
// are transposed through a block-local LDS tile st[32][224], then flushed
// with WIDE coalesced agent-coherent stores (global_store_dwordx4 sc0 sc1)
// -- fixes R5's scattered byte-atomic disaster. Last-block-per-b tail (16th
// arriver via atomicAdd) reads slab/xxp agent-coherently and runs the
// radial+W epilogue for rows b*32..b*32+31 in-register.
__global__ __launch_bounds__(256, 2) void rbf_main(
    const float* __restrict__ x, const uint8_t* __restrict__ cf8,
    uint8_t* __restrict__ slab, float* __restrict__ xxp,
    uint32_t* __restrict__ cnt, const float* __restrict__ ccp,
    const float* __restrict__ sigma, const float* __restrict__ W,
    const float* __restrict__ bias, float* __restrict__ out)
{
    __shared__ uint8_t sx[2][BT * BK];     //  8 KB
    __shared__ uint8_t sc[2][MPAD * BK];   // 56 KB  (64 KB total -> 2 blocks/CU)

    const int t    = threadIdx.x;
    const int k    = blockIdx.x;
    const int b    = blockIdx.y;
    const int wave = t >> 6, lane = t & 63;
    const int quad = lane >> 4, mrow = lane & 15;
    const int qh = quad >> 1, ql = quad & 1;
    const int s2 = (mrow >> 1) & 7;
    const int rt  = wave & 1;           // row-tile (16 rows)
    const int cth = wave >> 1;          // ct-half (7 tiles)

    floatx4 acc[NCT];
    const floatx4 z4 = {0.f, 0.f, 0.f, 0.f};
#pragma unroll
    for (int i = 0; i < NCT; ++i) acc[i] = z4;

    // ---- c-DMA lane source pointers (R8-verified mapping).
    const int oE = (((lane & 7) ^ (lane >> 4)) & 7) * 16;
    const int oO = ((((lane & 7) ^ (lane >> 4)) ^ 4) & 7) * 16;
    const uint8_t* cpbE = cf8 + (size_t)(lane >> 3) * D_SZ + (size_t)k * KCH + oE;
    const uint8_t* cpbO = cf8 + (size_t)(lane >> 3) * D_SZ + (size_t)k * KCH + oO;

    // ---- issue iter-0 c-DMA into sc[0] (in flight across whole x prologue)
#pragma unroll
    for (int jj = 0; jj < 7; ++jj) {
        const int cr = wave * 7 + jj;
        const uint8_t* p = ((cr & 1) ? cpbO : cpbE) + (size_t)cr * 8 * D_SZ;
        gload_lds16(p, &sc[0][cr * 1024]);
    }

    // ---- x prologue: 8 threads/row, 16 floats each per iter -> fp8 uint4
    const int xr = t >> 3;              // staging row 0..31
    const int xc = t & 7;               // 16-float column group
    const float* xp = x + (size_t)(b * BT + xr) * D_SZ + (size_t)k * KCH + xc * 16;

    uint4 xw[NIT];
    float sxx = 0.f;
#pragma unroll
    for (int it = 0; it < NIT; ++it) {
        float4 v0 = *(const float4*)(xp + it * BK + 0);
        float4 v1 = *(const float4*)(xp + it * BK + 4);
        float4 v2 = *(const float4*)(xp + it * BK + 8);
        float4 v3 = *(const float4*)(xp + it * BK + 12);
        sxx += v0.x*v0.x + v0.y*v0.y + v0.z*v0.z + v0.w*v0.w
             + v1.x*v1.x + v1.y*v1.y + v1.z*v1.z + v1.w*v1.w
             + v2.x*v2.x + v2.y*v2.y + v2.z*v2.z + v2.w*v2.w
             + v3.x*v3.x + v3.y*v3.y + v3.z*v3.z + v3.w*v3.w;
        xw[it] = make_uint4(pk8x4(v0), pk8x4(v1), pk8x4(v2), pk8x4(v3));
    }
    // sx dest: row xr, chunk16 = xc ^ ((xr>>1)&7)
    const int sxoff = xr * BK + ((xc ^ ((xr >> 1) & 7)) & 7) * 16;

    // ---- fragment offsets (shared by A and B; rows have same s2 law)
    int boff[4];
#pragma unroll
    for (int ks = 0; ks < 4; ++ks)
        boff[ks] = (((ks * 2 + qh) ^ s2) & 7) * 16 + ql * 8;
    const int aoff  = (rt * 16 + mrow) * BK;
    const int boff0 = (cth * 7 * 16 + mrow) * BK;

    *(uint4*)&sx[0][sxoff] = xw[0];
    __syncthreads();   // drains DMA(0) + sx writes

#pragma unroll
    for (int it = 0; it < NIT; ++it) {
        const int cur = it & 1;
        // issue next-iter staging first (flies during MFMA phase)
        if (it + 1 < NIT) {
#pragma unroll
            for (int jj = 0; jj < 7; ++jj) {
                const int cr = wave * 7 + jj;
                const uint8_t* p = ((cr & 1) ? cpbO : cpbE)
                                 + (size_t)cr * 8 * D_SZ + (it + 1) * BK;
                gload_lds16(p, &sc[cur ^ 1][cr * 1024]);
            }
            *(uint4*)&sx[cur ^ 1][sxoff] = xw[it + 1];
        }
        // MFMA phase on current buffers
#pragma unroll
        for (int ks = 0; ks < 4; ++ks) {
            const long a = *(const long*)(&sx[cur][aoff] + boff[ks]);
#pragma unroll
            for (int ct = 0; ct < NCT; ++ct) {
                const long bv = *(const long*)(&sc[cur][boff0] + ct * 16 * BK + boff[ks]);
                acc[ct] = __builtin_amdgcn_mfma_f32_16x16x32_fp8_fp8(a, bv, acc[ct], 0, 0, 0);
            }
        }
        __syncthreads();
    }

    // ---- slab write, stage 1: fp8 results -> block-local LDS tile st[32][224]
    // (sx is dead now; 7168 B fits in its 8 KB). C/D: col=lane&15, row=quad*4+reg.
    uint8_t* st = &sx[0][0];
    {
        const int gil = rt * 16 + quad * 4;   // local row base 0..31
#pragma unroll
        for (int ct = 0; ct < NCT; ++ct) {
            const int gj = (cth * 7 + ct) * 16 + mrow;
            const int p01 = __builtin_amdgcn_cvt_pk_fp8_f32(acc[ct][0], acc[ct][1], 0, false);
            const int p23 = __builtin_amdgcn_cvt_pk_fp8_f32(acc[ct][2], acc[ct][3], 0, false);
            st[(gil + 0) * SROW + gj] = (uint8_t)(p01 & 0xff);
            st[(gil + 1) * SROW + gj] = (uint8_t)((p01 >> 8) & 0xff);
            st[(gil + 2) * SROW + gj] = (uint8_t)(p23 & 0xff);
            st[(gil + 3) * SROW + gj] = (uint8_t)((p23 >> 8) & 0xff);
        }
        // xx partials: 8 staging threads per row -> 1 agent store (4 B, few)
        sxx += __shfl_down(sxx, 4);
        sxx += __shfl_down(sxx, 2);
        sxx += __shfl_down(sxx, 1);
        if ((t & 7) == 0) ST_AGENT(&xxp[(size_t)(b * BT + xr) * KC + k], sxx);
    }
    __syncthreads();

    // ---- slab write, stage 2: cooperative WIDE coalesced agent stores.
    // 32 rows x 224 B = 448 uint4; element e -> row e/14, 16B-chunk e%14.
    {
#pragma unroll
        for (int e = t; e < 448; e += 256) {
            const int r = e / 14, c4 = e % 14;
            uint32x4 v = *(const uint32x4*)(st + e * 16);   // e*16 == r*224 + c4*16
            uint8_t* dst = slab + (size_t)(b * BT + r) * SLROW
                         + (size_t)k * SROW + c4 * 16;
            asm volatile("global_store_dwordx4 %0, %1, off sc0 sc1"
                         :: "v"(dst), "v"(v) : "memory");
        }
    }

    // ---- last-block-per-b fin tail (no cache-flush fences) ----------------
    asm volatile("s_waitcnt vmcnt(0)" ::: "memory");  // stores ack'd at L3
    __syncthreads();
    int* flag = (int*)&sc[0][0];        // sc dead; LDS flag
    if (t == 0) {
        const uint32_t old = atomicAdd(&cnt[b], 1u);
        *flag = (old == (uint32_t)(KC - 1)) ? 1 : 0;
    }
    __syncthreads();
    if (*flag == 0) return;             // not last -> done

    const float b0 = bias[0], b1 = bias[1];
    // wave handles rows b*32 + wave*8 .. +7; lane owns columns 4*lane..4*lane+3
#pragma unroll
    for (int r = 0; r < 8; ++r) {
        const int i = b * BT + wave * 8 + r;

        // xx_i = sum over KC chunks (agent-coherent reads)
        float xv = (lane < KC) ? LD_AGENT(&xxp[(size_t)i * KC + lane]) : 0.f;
#pragma unroll
        for (int off = 32; off > 0; off >>= 1) xv += __shfl_down(xv, off);
        const float xxi = __shfl(xv, 0);

        // jtot for 4 columns: sum over KC of fp8 slab (coalesced dword reads)
        float jt0 = 0.f, jt1 = 0.f, jt2 = 0.f, jt3 = 0.f;
        if (lane < 56) {
            const uint8_t* sp = slab + (size_t)i * SLROW + lane * 4;
#pragma unroll
            for (int kk = 0; kk < KC; ++kk) {
                const int v = LD_AGENT((const int*)(sp + kk * SROW));
                jt0 += __builtin_amdgcn_cvt_f32_fp8(v, 0);
                jt1 += __builtin_amdgcn_cvt_f32_fp8(v, 1);
                jt2 += __builtin_amdgcn_cvt_f32_fp8(v, 2);
                jt3 += __builtin_amdgcn_cvt_f32_fp8(v, 3);
            }
        }

        // epilogue for the 4 owned columns
        float a0 = 0.f, a1 = 0.f;
        const float jt[4] = { jt0, jt1, jt2, jt3 };
#pragma unroll
        for (int e = 0; e < 4; ++e) {
            const int j = lane * 4 + e;
            if (j < M_SZ) {
                const float ccj = ccp[j * 2] + ccp[j * 2 + 1];
                const float d2 = fmaxf(xxi + ccj - 2.f * jt[e], 0.f);
                const float sg = sigma[j];
                const float rad = __expf(-sqrtf(d2) / (sg * sg));
                a0 += rad * W[j];
                a1 += rad * W[M_SZ + j];
            }
        }
#pragma unroll
        for (int off = 32; off > 0; off >>= 1) {
            a0 += __shfl_down(a0, off);
            a1 += __shfl_down(a1, off);
        }
        if (lane == 0) {
            out[i * 2 + 0] = a0 + b0;
            out[i * 2 + 1] = a1 + b1;
        }
    }
}

// ---------------------------------------------------------------------------
extern "C" void kernel_launch(void* const* d_in, const int* in_sizes, int n_in,
                              void* d_out, int out_size, void* d_ws, size_t ws_size,
                              hipStream_t stream)
{
    const float* x     = (const float*)d_in[0];
    const float* c     = (const float*)d_in[1];
    const float* sigma = (const float*)d_in[2];
    const float* W     = (const float*)d_in[3];
    const float* bias  = (const float*)d_in[4];
    float* out = (float*)d_out;

    char* ws = (char*)d_ws;
    uint8_t*  cf8  = (uint8_t*)(ws + CBF_OFF);
    float*    xxp  = (float*)(ws + XXP_OFF);
    float*    ccp  = (float*)(ws + CCP_OFF);
    uint8_t*  slab = (uint8_t*)(ws + SLAB_OFF);
    uint32_t* cnt  = (uint32_t*)(ws + CNT_OFF);

    rbf_prep<<<MPAD * 2, 256, 0, stream>>>(c, cf8, ccp, cnt);
    rbf_main<<<dim3(KC, NB), 256, 0, stream>>>(x, cf8, slab, xxp, cnt,
                                               ccp, sigma, W, bias, out);
}

// Round 7
// 107.849 us; speedup vs baseline: 1.7745x; 1.1521x over previous
//
#include <hip/hip_runtime.h>
#include <hip/hip_bf16.h>
#include <stdint.h>

#define B_SZ 1024
#define M_SZ 209
#define MPAD 224            // padded M rows (14 * 16)
#define D_SZ 12288
#define KC   16             // split-K chunks
#define KCH  768            // K elems per chunk (D/KC)
#define BK   128            // K per staging iteration (fp8 bytes == elems)
#define NIT  (KCH / BK)     // 6
#define NB   32             // B splits -> grid (16,32) = 512 blocks = 2/CU
#define BT   32             // B rows per block
#define NCT  7              // 16-wide col tiles per wave (ct-half)
#define SROW 224            // slab k-stride (fp8 BYTES)
#define SLROW (KC * SROW)   // 3584

// ws byte offsets
#define CBF_OFF  0u                                   // c fp8 [224][12288] (2.75 MB)
#define XXP_OFF  (MPAD * D_SZ)                        // xx partials [B][KC] f32 (64 KB)
#define CCP_OFF  (XXP_OFF + B_SZ * KC * 4)            // cc halves [224][2] f32
#define SLAB_OFF (CCP_OFF + MPAD * 2 * 4)             // slab [B][KC][224] fp8 (3.67 MB)

typedef __attribute__((ext_vector_type(8))) short short8;
typedef __attribute__((ext_vector_type(4))) float floatx4;

__device__ __forceinline__ uint32_t pk8x4(const float4& v) {
    int d = __builtin_amdgcn_cvt_pk_fp8_f32(v.x, v.y, 0, false);
    d     = __builtin_amdgcn_cvt_pk_fp8_f32(v.z, v.w, d, true);
    return (uint32_t)d;
}

__device__ __forceinline__ void gload_lds16(const void* g, void* l) {
    __builtin_amdgcn_global_load_lds(
        (const __attribute__((address_space(1))) void*)g,
        (__attribute__((address_space(3))) void*)l, 16, 0, 0);
}

// ---------------------------------------------------------------------------
// prepass: c fp32 -> fp8 e4m3 (padded to 224 rows, zeros) + ||c||^2 halves.
__global__ __launch_bounds__(256) void rbf_prep(
    const float* __restrict__ c, uint8_t* __restrict__ cf8,
    float* __restrict__ ccp)
{
    __shared__ float red[4];
    const int j = blockIdx.x >> 1, h = blockIdx.x & 1;
    const int t = threadIdx.x;
    const int base = h * (D_SZ / 2);
    uint8_t* dst = cf8 + (size_t)j * D_SZ + base;
    float s = 0.f;
    if (j < M_SZ) {
        const float* src = c + (size_t)j * D_SZ + base;
        for (int i = t * 8; i < D_SZ / 2; i += 2048) {
            float4 v0 = *(const float4*)(src + i);
            float4 v1 = *(const float4*)(src + i + 4);
            s += v0.x*v0.x + v0.y*v0.y + v0.z*v0.z + v0.w*v0.w
               + v1.x*v1.x + v1.y*v1.y + v1.z*v1.z + v1.w*v1.w;
            uint2 w = { pk8x4(v0), pk8x4(v1) };
            *(uint2*)(dst + i) = w;
        }
    } else {
        uint2 zz = {0u, 0u};
        for (int i = t * 8; i < D_SZ / 2; i += 2048) *(uint2*)(dst + i) = zz;
    }
#pragma unroll
    for (int off = 32; off > 0; off >>= 1) s += __shfl_down(s, off);
    if ((t & 63) == 0) red[t >> 6] = s;
    __syncthreads();
    if (t == 0) ccp[j * 2 + h] = red[0] + red[1] + red[2] + red[3];
}

// ---------------------------------------------------------------------------
// main: split-K distance GEMM, 16x16x32 fp8_fp8 MFMA, BT=32, 2 blocks/CU.
// PIPELINED x staging: only 2 raw x-subtiles live in registers; subtile it+1
// is converted and subtile it+2's loads are issued INSIDE iteration it, so
// each per-iter barrier drains ~4 x-loads + 14 c-DMAs (covered by the MFMA
// phase) instead of R1's all-24-x-loads drain before the first MFMA.
__global__ __launch_bounds__(256, 2) void rbf_main(
    const float* __restrict__ x, const uint8_t* __restrict__ cf8,
    uint8_t* __restrict__ slab, float* __restrict__ xxp)
{
    __shared__ uint8_t sx[2][BT * BK];     //  8 KB
    __shared__ uint8_t sc[2][MPAD * BK];   // 56 KB  (64 KB total -> 2 blocks/CU)

    const int t    = threadIdx.x;
    const int k    = blockIdx.x;
    const int b    = blockIdx.y;
    const int wave = t >> 6, lane = t & 63;
    const int quad = lane >> 4, mrow = lane & 15;
    const int qh = quad >> 1, ql = quad & 1;
    const int s2 = (mrow >> 1) & 7;
    const int rt  = wave & 1;           // row-tile (16 rows)
    const int cth = wave >> 1;          // ct-half (7 tiles)

    floatx4 acc[NCT];
    const floatx4 z4 = {0.f, 0.f, 0.f, 0.f};
#pragma unroll
    for (int i = 0; i < NCT; ++i) acc[i] = z4;

    // ---- c-DMA lane source pointers (R8-verified mapping).
    const int oE = (((lane & 7) ^ (lane >> 4)) & 7) * 16;
    const int oO = ((((lane & 7) ^ (lane >> 4)) ^ 4) & 7) * 16;
    const uint8_t* cpbE = cf8 + (size_t)(lane >> 3) * D_SZ + (size_t)k * KCH + oE;
    const uint8_t* cpbO = cf8 + (size_t)(lane >> 3) * D_SZ + (size_t)k * KCH + oO;

    // ---- issue iter-0 c-DMA into sc[0] first (in flight across x prologue)
#pragma unroll
    for (int jj = 0; jj < 7; ++jj) {
        const int cr = wave * 7 + jj;
        const uint8_t* p = ((cr & 1) ? cpbO : cpbE) + (size_t)cr * 8 * D_SZ;
        gload_lds16(p, &sc[0][cr * 1024]);
    }

    // ---- x pipeline prologue: issue subtile 0 and 1 raw loads, convert st0.
    const int xr = t >> 3;              // staging row 0..31
    const int xc = t & 7;               // 16-float column group
    const float* xp = x + (size_t)(b * BT + xr) * D_SZ + (size_t)k * KCH + xc * 16;

    float4 ra0 = *(const float4*)(xp + 0);
    float4 ra1 = *(const float4*)(xp + 4);
    float4 ra2 = *(const float4*)(xp + 8);
    float4 ra3 = *(const float4*)(xp + 12);
    float4 rb0 = *(const float4*)(xp + BK + 0);
    float4 rb1 = *(const float4*)(xp + BK + 4);
    float4 rb2 = *(const float4*)(xp + BK + 8);
    float4 rb3 = *(const float4*)(xp + BK + 12);

    float sxx = ra0.x*ra0.x + ra0.y*ra0.y + ra0.z*ra0.z + ra0.w*ra0.w
              + ra1.x*ra1.x + ra1.y*ra1.y + ra1.z*ra1.z + ra1.w*ra1.w
              + ra2.x*ra2.x + ra2.y*ra2.y + ra2.z*ra2.z + ra2.w*ra2.w
              + ra3.x*ra3.x + ra3.y*ra3.y + ra3.z*ra3.z + ra3.w*ra3.w;

    // sx dest: row xr, chunk16 = xc ^ ((xr>>1)&7)
    const int sxoff = xr * BK + ((xc ^ ((xr >> 1) & 7)) & 7) * 16;
    {
        uint4 xw0 = make_uint4(pk8x4(ra0), pk8x4(ra1), pk8x4(ra2), pk8x4(ra3));
        *(uint4*)&sx[0][sxoff] = xw0;
    }

    // ---- fragment offsets (shared by A and B; rows have same s2 law)
    int boff[4];
#pragma unroll
    for (int ks = 0; ks < 4; ++ks)
        boff[ks] = (((ks * 2 + qh) ^ s2) & 7) * 16 + ql * 8;
    const int aoff  = (rt * 16 + mrow) * BK;
    const int boff0 = (cth * 7 * 16 + mrow) * BK;

    __syncthreads();   // drains DMA(0) + sx0 write + st0/st1 x-loads

#pragma unroll
    for (int it = 0; it < NIT; ++it) {
        const int cur = it & 1;
        if (it + 1 < NIT) {
            // convert subtile it+1 (loaded >=1 iteration ago) -> sx[cur^1]
            sxx += rb0.x*rb0.x + rb0.y*rb0.y + rb0.z*rb0.z + rb0.w*rb0.w
                 + rb1.x*rb1.x + rb1.y*rb1.y + rb1.z*rb1.z + rb1.w*rb1.w
                 + rb2.x*rb2.x + rb2.y*rb2.y + rb2.z*rb2.z + rb2.w*rb2.w
                 + rb3.x*rb3.x + rb3.y*rb3.y + rb3.z*rb3.z + rb3.w*rb3.w;
            uint4 xwn = make_uint4(pk8x4(rb0), pk8x4(rb1), pk8x4(rb2), pk8x4(rb3));
            *(uint4*)&sx[cur ^ 1][sxoff] = xwn;
            // issue subtile it+2 raw loads (covered by this + next MFMA phase)
            if (it + 2 < NIT) {
                const float* q = xp + (it + 2) * BK;
                rb0 = *(const float4*)(q + 0);
                rb1 = *(const float4*)(q + 4);
                rb2 = *(const float4*)(q + 8);
                rb3 = *(const float4*)(q + 12);
            }
            // c-DMA it+1 into sc[cur^1]
#pragma unroll
            for (int jj = 0; jj < 7; ++jj) {
                const int cr = wave * 7 + jj;
                const uint8_t* p = ((cr & 1) ? cpbO : cpbE)
                                 + (size_t)cr * 8 * D_SZ + (it + 1) * BK;
                gload_lds16(p, &sc[cur ^ 1][cr * 1024]);
            }
        }
        // MFMA phase on current buffers
#pragma unroll
        for (int ks = 0; ks < 4; ++ks) {
            const long a = *(const long*)(&sx[cur][aoff] + boff[ks]);
#pragma unroll
            for (int ct = 0; ct < NCT; ++ct) {
                const long bv = *(const long*)(&sc[cur][boff0] + ct * 16 * BK + boff[ks]);
                acc[ct] = __builtin_amdgcn_mfma_f32_16x16x32_fp8_fp8(a, bv, acc[ct], 0, 0, 0);
            }
        }
        __syncthreads();
    }

    // ---- slab write: [i][k][224] fp8 e4m3. C/D: col=lane&15, row=quad*4+reg
    {
        uint8_t* sd = slab + (size_t)k * SROW;
        const int gi0 = b * BT + rt * 16 + quad * 4;
#pragma unroll
        for (int ct = 0; ct < NCT; ++ct) {
            const int gj = (cth * 7 + ct) * 16 + mrow;
            const int p01 = __builtin_amdgcn_cvt_pk_fp8_f32(acc[ct][0], acc[ct][1], 0, false);
            const int p23 = __builtin_amdgcn_cvt_pk_fp8_f32(acc[ct][2], acc[ct][3], 0, false);
            uint8_t* wb = sd + (size_t)gi0 * SLROW + gj;
            wb[0]                 = (uint8_t)(p01 & 0xff);
            wb[SLROW]             = (uint8_t)((p01 >> 8) & 0xff);
            wb[2 * (size_t)SLROW] = (uint8_t)(p23 & 0xff);
            wb[3 * (size_t)SLROW] = (uint8_t)((p23 >> 8) & 0xff);
        }
        sxx += __shfl_down(sxx, 4);
        sxx += __shfl_down(sxx, 2);
        sxx += __shfl_down(sxx, 1);
        if ((t & 7) == 0) xxp[(size_t)(b * BT + xr) * KC + k] = sxx;
    }
}

// ---------------------------------------------------------------------------
// finalize: one block per row; octet k-reduction of fp8 slab, then radial
// + W epilogue.
__global__ __launch_bounds__(256) void rbf_fin(
    const uint8_t* __restrict__ slab, const float* __restrict__ xxp,
    const float* __restrict__ ccp, const float* __restrict__ sigma,
    const float* __restrict__ W, const float* __restrict__ bias,
    float* __restrict__ out)
{
    __shared__ float jpart[MPAD * 9];
    __shared__ float jtot[MPAD];
    __shared__ float xsh;

    const int t = threadIdx.x;
    const int i = blockIdx.x;

    if (t < 64) {
        float xv = (t < KC) ? xxp[(size_t)i * KC + t] : 0.f;
#pragma unroll
        for (int off = 32; off > 0; off >>= 1) xv += __shfl_down(xv, off);
        if (t == 0) xsh = xv;
    }

    const int o = t % 28, g = t / 28;   // 28 octets x 9 k-groups = 252 threads
    if (t < 252) {
        const uint8_t* sp = slab + (size_t)i * SLROW + o * 8;
        float s8[8] = {0.f,0.f,0.f,0.f,0.f,0.f,0.f,0.f};
        for (int kk = g; kk < KC; kk += 9) {
            uint2 v = *(const uint2*)(sp + (size_t)kk * SROW);
            s8[0] += __builtin_amdgcn_cvt_f32_fp8((int)v.x, 0);
            s8[1] += __builtin_amdgcn_cvt_f32_fp8((int)v.x, 1);
            s8[2] += __builtin_amdgcn_cvt_f32_fp8((int)v.x, 2);
            s8[3] += __builtin_amdgcn_cvt_f32_fp8((int)v.x, 3);
            s8[4] += __builtin_amdgcn_cvt_f32_fp8((int)v.y, 0);
            s8[5] += __builtin_amdgcn_cvt_f32_fp8((int)v.y, 1);
            s8[6] += __builtin_amdgcn_cvt_f32_fp8((int)v.y, 2);
            s8[7] += __builtin_amdgcn_cvt_f32_fp8((int)v.y, 3);
        }
#pragma unroll
        for (int e = 0; e < 8; ++e) jpart[(o * 8 + e) * 9 + g] = s8[e];
    }
    __syncthreads();

    if (t < MPAD) {
        float d = 0.f;
#pragma unroll
        for (int g2 = 0; g2 < 9; ++g2) d += jpart[t * 9 + g2];
        jtot[t] = d;
    }
    __syncthreads();

    if (t < 64) {
        const float xxi = xsh;
        float a0 = 0.f, a1 = 0.f;
        for (int j = t; j < M_SZ; j += 64) {
            const float ccj = ccp[j * 2] + ccp[j * 2 + 1];
            float d2 = fmaxf(xxi + ccj - 2.f * jtot[j], 0.f);
            float sg = sigma[j];
            float rad = __expf(-sqrtf(d2) / (sg * sg));
            a0 += rad * W[j];
            a1 += rad * W[M_SZ + j];
        }
#pragma unroll
        for (int off = 32; off > 0; off >>= 1) {
            a0 += __shfl_down(a0, off);
            a1 += __shfl_down(a1, off);
        }
        if (t == 0) {
            out[i * 2 + 0] = a0 + bias[0];
            out[i * 2 + 1] = a1 + bias[1];
        }
    }
}

// ---------------------------------------------------------------------------
extern "C" void kernel_launch(void* const* d_in, const int* in_sizes, int n_in,
                              void* d_out, int out_size, void* d_ws, size_t ws_size,
                              hipStream_t stream)
{
    const float* x     = (const float*)d_in[0];
    const float* c     = (const float*)d_in[1];
    const float* sigma = (const float*)d_in[2];
    const float* W     = (const float*)d_in[3];
    const float* bias  = (const float*)d_in[4];
    float* out = (float*)d_out;

    char* ws = (char*)d_ws;
    uint8_t* cf8  = (uint8_t*)(ws + CBF_OFF);
    float*   xxp  = (float*)(ws + XXP_OFF);
    float*   ccp  = (float*)(ws + CCP_OFF);
    uint8_t* slab = (uint8_t*)(ws + SLAB_OFF);

    rbf_prep<<<MPAD * 2, 256, 0, stream>>>(c, cf8, ccp);
    rbf_main<<<dim3(KC, NB), 256, 0, stream>>>(x, cf8, slab, xxp);
    rbf_fin<<<B_SZ, 256, 0, stream>>>(slab, xxp, ccp, sigma, W, bias, out);
}